// Round 1
// baseline (2937.670 us; speedup 1.0000x reference)
//
#include <hip/hip_runtime.h>

// Problem dims (fixed by reference)
#define LL 128      // memory length
#define BB 16       // batch
#define DD 512      // memory dim
#define HH 512      // hidden
#define VV 16000    // vocab
#define TT 32       // steps
#define NHEADS 8
#define DKK 64      // head dim

// workspace layout (float offsets)
#define WS_K 0
#define WS_V (LL*BB*HH)
#define WS_HID0 (2*LL*BB*HH)
#define WS_HID1 (WS_HID0 + BB*HH)
#define WS_CTX  (WS_HID1 + BB*HH)
#define WS_SLOTS_F (WS_CTX + BB*HH)   // uint64 argmax slots start here (byte off = *4, 8B aligned)

#define OUT_HID_OFF ((size_t)TT*BB*VV)
#define OUT_SC_OFF  ((size_t)TT*BB*VV + (size_t)TT*BB*HH)

// slots[t*BB + b]: hi32 = monotonic-encoded float, lo32 = 0xFFFFFFFF - col
// (atomicMax picks max value; ties -> smallest col = jnp.argmax first-occurrence)

__global__ void init_kernel(float* __restrict__ ws) {
    int tid = threadIdx.x;
    for (int i = tid; i < BB*HH; i += blockDim.x) ws[WS_HID0 + i] = 0.f;
    unsigned long long* slots = (unsigned long long*)(ws + WS_SLOTS_F);
    for (int i = tid; i < (TT+1)*BB; i += blockDim.x)
        slots[i] = (i < BB) ? 0xFFFFFFFFull : 0ull;   // step0: argmax(zeros)=0
}

// K = memory@Wk + bk, V = memory@Wv + bv  -> ws, shape (L*B, H), row = l*B+b
// 256 blocks: blk<128 -> K row-group, else V. Each block: 16 rows x all 512 cols.
__global__ __launch_bounds__(256) void kv_kernel(const float* __restrict__ mem,
        const float* __restrict__ Wk, const float* __restrict__ bk,
        const float* __restrict__ Wv, const float* __restrict__ bv,
        float* __restrict__ ws) {
    int blk = blockIdx.x;
    int isV = blk >= 128;
    int rg = blk & 127;
    const float* W = isV ? Wv : Wk;
    const float* bias = isV ? bv : bk;
    float* out = ws + (isV ? WS_V : WS_K);
    int rowBase = rg * 16;
    int c0 = threadIdx.x * 2;
    __shared__ float As[16*512];
    for (int i = threadIdx.x; i < 16*512; i += 256)
        As[i] = mem[rowBase*512 + i];
    __syncthreads();
    float acc0[16], acc1[16];
    #pragma unroll
    for (int r = 0; r < 16; ++r) { acc0[r] = 0.f; acc1[r] = 0.f; }
    for (int k = 0; k < 512; ++k) {
        float2 w2 = *(const float2*)(W + (size_t)k*512 + c0);
        #pragma unroll
        for (int r = 0; r < 16; ++r) {
            float a = As[r*512 + k];
            acc0[r] += a * w2.x;
            acc1[r] += a * w2.y;
        }
    }
    float2 bc = *(const float2*)(bias + c0);
    #pragma unroll
    for (int r = 0; r < 16; ++r) {
        float2 o; o.x = acc0[r] + bc.x; o.y = acc1[r] + bc.y;
        *(float2*)(out + (size_t)(rowBase + r)*512 + c0) = o;
    }
}

// One block per batch b, 512 threads.
// 1) read argmax slot -> embedded = emb[idx]; query = [embedded, hid]
// 2) qh = query@Wq + bq  (k-split x4, float4 weight loads)
// 3) scores per (head,l), softmax per head (wave per head)
// 4) sc = mean over heads -> masked scores output
// 5) ctx = p @ V -> ws
__global__ __launch_bounds__(512) void attn_kernel(
        const float* __restrict__ emb, const float* __restrict__ Wq,
        const float* __restrict__ bq, const int* __restrict__ olen,
        float* __restrict__ ws, float* __restrict__ out, int t) {
    int b = blockIdx.x;
    int tid = threadIdx.x;
    const float* hid = ws + ((t & 1) ? WS_HID1 : WS_HID0);
    unsigned long long* slots = (unsigned long long*)(ws + WS_SLOTS_F);
    __shared__ float q[2*HH];
    __shared__ float qh[HH];
    __shared__ float part[4*HH];
    __shared__ float sbuf[NHEADS*LL];

    unsigned long long slot = slots[t*BB + b];
    unsigned idx = 0xFFFFFFFFu - (unsigned)(slot & 0xFFFFFFFFull);
    q[tid] = emb[(size_t)idx * HH + tid];
    q[HH + tid] = hid[b*HH + tid];
    __syncthreads();

    {   // qproj: thread = (col-quad cq, k-quarter ks)
        int cq = tid & 127, ks = tid >> 7;
        int c0 = cq * 4;
        float ax=0.f, ay=0.f, az=0.f, aw=0.f;
        int kbeg = ks * 256;
        const float* wp = Wq + (size_t)kbeg*HH + c0;
        for (int kk = 0; kk < 256; ++kk) {
            float x = q[kbeg + kk];
            float4 w4 = *(const float4*)(wp + (size_t)kk*HH);
            ax += x*w4.x; ay += x*w4.y; az += x*w4.z; aw += x*w4.w;
        }
        float4 a4; a4.x=ax; a4.y=ay; a4.z=az; a4.w=aw;
        *(float4*)(part + ks*HH + c0) = a4;
    }
    __syncthreads();
    qh[tid] = bq[tid] + part[tid] + part[HH + tid] + part[2*HH + tid] + part[3*HH + tid];
    __syncthreads();

    // scores: s = h*128 + l
    const float* Kp = ws + WS_K;
    for (int s = tid; s < NHEADS*LL; s += 512) {
        int h = s >> 7, l = s & 127;
        const float4* kr = (const float4*)(Kp + ((size_t)(l*BB + b))*HH + h*DKK);
        const float4* qr = (const float4*)(qh + h*DKK);
        float acc = 0.f;
        #pragma unroll
        for (int j = 0; j < 16; ++j) {
            float4 kv4 = kr[j]; float4 q4 = qr[j];
            acc += q4.x*kv4.x + q4.y*kv4.y + q4.z*kv4.z + q4.w*kv4.w;
        }
        sbuf[s] = acc * 0.125f;   // 1/sqrt(64)
    }
    __syncthreads();

    {   // softmax: wave w handles head w; lane covers l and l+64
        int w = tid >> 6, lane = tid & 63;
        float s0 = sbuf[w*LL + lane], s1 = sbuf[w*LL + 64 + lane];
        float m = fmaxf(s0, s1);
        #pragma unroll
        for (int off = 32; off; off >>= 1) m = fmaxf(m, __shfl_xor(m, off));
        float e0 = expf(s0 - m), e1 = expf(s1 - m);
        float sum = e0 + e1;
        #pragma unroll
        for (int off = 32; off; off >>= 1) sum += __shfl_xor(sum, off);
        float inv = 1.f / sum;
        sbuf[w*LL + lane] = e0 * inv;
        sbuf[w*LL + 64 + lane] = e1 * inv;
    }
    __syncthreads();

    bool active = t < olen[b];
    if (tid < LL) {
        float s = 0.f;
        #pragma unroll
        for (int h = 0; h < NHEADS; ++h) s += sbuf[h*LL + tid];
        out[OUT_SC_OFF + ((size_t)t*BB + b)*LL + tid] = active ? s*0.125f : 0.f;
    }

    {   // ctx: col = tid, head = tid>>6
        const float* Vp = ws + WS_V;
        int h = tid >> 6;
        const float* p = sbuf + h*LL;
        float acc = 0.f;
        #pragma unroll 4
        for (int l = 0; l < LL; ++l)
            acc += p[l] * Vp[((size_t)(l*BB + b))*HH + tid];
        ws[WS_CTX + b*HH + tid] = acc;
    }
}

// GRU: 64 blocks = 16 b x 4 col-groups (128 cols). 256 thr = 4 waves k-split.
__global__ __launch_bounds__(256) void gru_kernel(
        const float* __restrict__ Wih, const float* __restrict__ bih,
        const float* __restrict__ Whh, const float* __restrict__ bhh,
        const int* __restrict__ olen, float* __restrict__ ws,
        float* __restrict__ out, int t) {
    int blk = blockIdx.x;
    int b = blk >> 2, cg = blk & 3;
    int tid = threadIdx.x;
    int w = tid >> 6, lane = tid & 63;
    const float* hid = ws + ((t & 1) ? WS_HID1 : WS_HID0);
    float* hidn = ws + ((t & 1) ? WS_HID0 : WS_HID1);
    const float* ctx = ws + WS_CTX;
    __shared__ float x_s[HH], h_s[HH];
    __shared__ float part[4*64*12];
    for (int i = tid; i < HH; i += 256) {
        x_s[i] = ctx[b*HH + i];
        h_s[i] = hid[b*HH + i];
    }
    __syncthreads();
    int c0 = cg*128 + lane*2;
    float ir0=0,ir1=0,iz0=0,iz1=0,in0=0,in1=0,hr0=0,hr1=0,hz0=0,hz1=0,hn0=0,hn1=0;
    int kbeg = w * 128;
    for (int kk = 0; kk < 128; ++kk) {
        int k = kbeg + kk;
        float x = x_s[k], hv = h_s[k];
        const float* wi = Wih + (size_t)k*3*HH;
        const float* wh = Whh + (size_t)k*3*HH;
        float2 wr = *(const float2*)(wi + c0);
        float2 wz = *(const float2*)(wi + HH + c0);
        float2 wn = *(const float2*)(wi + 2*HH + c0);
        ir0 += x*wr.x; ir1 += x*wr.y;
        iz0 += x*wz.x; iz1 += x*wz.y;
        in0 += x*wn.x; in1 += x*wn.y;
        wr = *(const float2*)(wh + c0);
        wz = *(const float2*)(wh + HH + c0);
        wn = *(const float2*)(wh + 2*HH + c0);
        hr0 += hv*wr.x; hr1 += hv*wr.y;
        hz0 += hv*wz.x; hz1 += hv*wz.y;
        hn0 += hv*wn.x; hn1 += hv*wn.y;
    }
    float* pp = part + (w*64 + lane)*12;
    pp[0]=ir0; pp[1]=ir1; pp[2]=iz0; pp[3]=iz1; pp[4]=in0; pp[5]=in1;
    pp[6]=hr0; pp[7]=hr1; pp[8]=hz0; pp[9]=hz1; pp[10]=hn0; pp[11]=hn1;
    __syncthreads();
    if (tid < 64) {
        float v[12];
        #pragma unroll
        for (int j = 0; j < 12; ++j)
            v[j] = part[(0*64+tid)*12+j] + part[(1*64+tid)*12+j]
                 + part[(2*64+tid)*12+j] + part[(3*64+tid)*12+j];
        int c = cg*128 + tid*2;
        bool active = t < olen[b];
        #pragma unroll
        for (int u = 0; u < 2; ++u) {
            int cc = c + u;
            float gi_r = v[0+u]  + bih[cc];
            float gi_z = v[2+u]  + bih[HH+cc];
            float gi_n = v[4+u]  + bih[2*HH+cc];
            float gh_r = v[6+u]  + bhh[cc];
            float gh_z = v[8+u]  + bhh[HH+cc];
            float gh_n = v[10+u] + bhh[2*HH+cc];
            float r = 1.f/(1.f + expf(-(gi_r + gh_r)));
            float z = 1.f/(1.f + expf(-(gi_z + gh_z)));
            float n = tanhf(gi_n + r*gh_n);
            float hprev = h_s[cc];
            float hnew = (1.f - z)*n + z*hprev;
            hidn[b*HH + cc] = hnew;
            out[OUT_HID_OFF + ((size_t)t*BB + b)*HH + cc] = active ? hnew : 0.f;
        }
    }
}

// logits = h_new @ Wf + bf; masked write to outputs; fused argmax via atomicMax.
// 250 blocks x 256 thr; block = 64 cols, thread = (col, 4 batches).
__global__ __launch_bounds__(256) void logits_kernel(
        const float* __restrict__ Wf, const float* __restrict__ bf,
        const int* __restrict__ olen, float* __restrict__ ws,
        float* __restrict__ out, int t) {
    __shared__ float hs[BB*HH];
    __shared__ unsigned long long am[BB*64];
    int tid = threadIdx.x;
    const float* hidn = ws + ((t & 1) ? WS_HID0 : WS_HID1);  // h_new of this step
    for (int i = tid; i < BB*HH; i += 256) hs[i] = hidn[i];
    __syncthreads();
    int colLocal = tid & 63, bg = tid >> 6;
    int col = blockIdx.x*64 + colLocal;
    const float* h0 = hs + (bg*4+0)*HH;
    const float* h1 = hs + (bg*4+1)*HH;
    const float* h2 = hs + (bg*4+2)*HH;
    const float* h3 = hs + (bg*4+3)*HH;
    float a0=0,a1=0,a2=0,a3=0;
    const float* wp = Wf + col;
    for (int k = 0; k < HH; k += 4) {
        float wv0 = wp[(size_t)(k+0)*VV];
        float wv1 = wp[(size_t)(k+1)*VV];
        float wv2 = wp[(size_t)(k+2)*VV];
        float wv3 = wp[(size_t)(k+3)*VV];
        float4 hv0 = *(const float4*)(h0 + k);
        float4 hv1 = *(const float4*)(h1 + k);
        float4 hv2 = *(const float4*)(h2 + k);
        float4 hv3 = *(const float4*)(h3 + k);
        a0 += wv0*hv0.x + wv1*hv0.y + wv2*hv0.z + wv3*hv0.w;
        a1 += wv0*hv1.x + wv1*hv1.y + wv2*hv1.z + wv3*hv1.w;
        a2 += wv0*hv2.x + wv1*hv2.y + wv2*hv2.z + wv3*hv2.w;
        a3 += wv0*hv3.x + wv1*hv3.y + wv2*hv3.z + wv3*hv3.w;
    }
    float bfc = bf[col];
    float vals[4] = {a0+bfc, a1+bfc, a2+bfc, a3+bfc};
    #pragma unroll
    for (int j = 0; j < 4; ++j) {
        int b = bg*4 + j;
        bool active = t < olen[b];
        out[((size_t)t*BB + b)*VV + col] = active ? vals[j] : 0.f;
        unsigned u = __float_as_uint(vals[j]);
        u = (u & 0x80000000u) ? ~u : (u | 0x80000000u);
        am[b*64 + colLocal] = ((unsigned long long)u << 32)
                            | (unsigned long long)(0xFFFFFFFFu - (unsigned)col);
    }
    __syncthreads();
    if (tid < BB) {
        unsigned long long m = 0ull;
        for (int i = 0; i < 64; ++i) {
            unsigned long long vv2 = am[tid*64 + i];
            m = vv2 > m ? vv2 : m;
        }
        unsigned long long* slots = (unsigned long long*)(ws + WS_SLOTS_F);
        atomicMax(&slots[(size_t)(t+1)*BB + tid], m);
    }
}

extern "C" void kernel_launch(void* const* d_in, const int* in_sizes, int n_in,
                              void* d_out, int out_size, void* d_ws, size_t ws_size,
                              hipStream_t stream) {
    const float* mem = (const float*)d_in[0];
    const float* emb = (const float*)d_in[1];
    const float* Wq  = (const float*)d_in[2];
    const float* bq  = (const float*)d_in[3];
    const float* Wk  = (const float*)d_in[4];
    const float* bk  = (const float*)d_in[5];
    const float* Wv  = (const float*)d_in[6];
    const float* bv  = (const float*)d_in[7];
    const float* Wih = (const float*)d_in[8];
    const float* bih = (const float*)d_in[9];
    const float* Whh = (const float*)d_in[10];
    const float* bhh = (const float*)d_in[11];
    const float* Wf  = (const float*)d_in[12];
    const float* bf  = (const float*)d_in[13];
    const int* olen  = (const int*)d_in[14];
    float* out = (float*)d_out;
    float* ws  = (float*)d_ws;

    hipLaunchKernelGGL(init_kernel, dim3(1), dim3(256), 0, stream, ws);
    hipLaunchKernelGGL(kv_kernel, dim3(256), dim3(256), 0, stream, mem, Wk, bk, Wv, bv, ws);
    for (int t = 0; t < TT; ++t) {
        hipLaunchKernelGGL(attn_kernel, dim3(BB), dim3(512), 0, stream,
                           emb, Wq, bq, olen, ws, out, t);
        hipLaunchKernelGGL(gru_kernel, dim3(64), dim3(256), 0, stream,
                           Wih, bih, Whh, bhh, olen, ws, out, t);
        hipLaunchKernelGGL(logits_kernel, dim3(250), dim3(256), 0, stream,
                           Wf, bf, olen, ws, out, t);
    }
}

// Round 2
// 2043.654 us; speedup vs baseline: 1.4375x; 1.4375x over previous
//
#include <hip/hip_runtime.h>

#define LL 128      // memory length
#define BB 16       // batch
#define HH 512      // hidden
#define VV 16000    // vocab
#define TT 32       // steps
#define NH 8        // heads
#define DK 64       // head dim

// workspace layout (float offsets)
#define WS_K 0
#define WS_V (LL*BB*HH)
#define WS_HID0 (2*LL*BB*HH)
#define WS_HID1 (WS_HID0 + BB*HH)
#define WS_CTX  (WS_HID1 + BB*HH)
#define WS_P    (WS_CTX + BB*HH)          // p[b][h][128]
#define WS_G    (WS_P + BB*NH*LL)         // gates[6][b][512] (pre-bias)
#define WS_SLOTS_F (WS_G + 6*BB*HH)       // uint64 argmax slots (8B aligned)

#define OUT_HID_OFF ((size_t)TT*BB*VV)
#define OUT_SC_OFF  (OUT_HID_OFF + (size_t)TT*BB*HH)

// slots[t*BB+b]: hi32 = monotonic float encoding, lo32 = 0xFFFFFFFF - col
// atomicMax -> max value, tie -> smallest col (jnp.argmax first occurrence)

// K|V projection: grid 2048 = 128 rowgroups(16 rows) x 16 coltiles(64 cols over K|V).
// Block 0 additionally does the per-call init (hid0 zero, argmax slots).
__global__ __launch_bounds__(256) void kv_kernel(const float* __restrict__ mem,
        const float* __restrict__ Wk, const float* __restrict__ bk,
        const float* __restrict__ Wv, const float* __restrict__ bv,
        float* __restrict__ ws) {
    int blk = blockIdx.x;
    int rg = blk >> 4, ct = blk & 15;
    int isV = ct >= 8;
    int colbase = (ct & 7) * 64;
    const float* W = isV ? Wv : Wk;
    const float* bias = isV ? bv : bk;
    float* outp = ws + (isV ? WS_V : WS_K);
    int rowbase = rg * 16;
    int tid = threadIdx.x;
    __shared__ float As[16*512];

    const float4* srcp = (const float4*)(mem + (size_t)rowbase*512);
    float4* dstp = (float4*)As;
    #pragma unroll
    for (int i = 0; i < 8; ++i) dstp[tid + 256*i] = srcp[tid + 256*i];

    if (blk == 0) {
        for (int i = tid; i < BB*HH; i += 256) ws[WS_HID0 + i] = 0.f;
        unsigned long long* slots = (unsigned long long*)(ws + WS_SLOTS_F);
        for (int i = tid; i < (TT+1)*BB; i += 256)
            slots[i] = (i < BB) ? 0xFFFFFFFFull : 0ull;   // step0 argmax(zeros)=0
    }
    __syncthreads();

    int cq = tid & 15, rq = tid >> 4;      // 16 col-quads x 16 row-quads? (rq 0..15 -> 4 rows? no: rq 0..15)
    // NOTE: 256 threads = 16 cq x 16 rq is wrong; we want 16 cq x 4 rq covering 16 rows.
    // Use: cq = tid & 15 (4 cols each), rq = (tid >> 4) & 3 (4 rows each), rep = tid >> 6 splits k.
    int rq4 = (tid >> 4) & 3;
    int kq = tid >> 6;                      // 0..3: k-quarter (128 k each)
    const float4* As4 = (const float4*)As;
    float acc[4][4];
    #pragma unroll
    for (int i = 0; i < 4; ++i) { acc[i][0]=0.f; acc[i][1]=0.f; acc[i][2]=0.f; acc[i][3]=0.f; }
    const float* wp = W + colbase + cq*4;
    for (int k4 = kq*32; k4 < kq*32 + 32; ++k4) {
        float4 a0 = As4[(rq4*4+0)*128 + k4];
        float4 a1 = As4[(rq4*4+1)*128 + k4];
        float4 a2 = As4[(rq4*4+2)*128 + k4];
        float4 a3 = As4[(rq4*4+3)*128 + k4];
        const float* wrow = wp + (size_t)(4*k4)*512;
        float4 w0 = *(const float4*)(wrow);
        float4 w1 = *(const float4*)(wrow + 512);
        float4 w2 = *(const float4*)(wrow + 1024);
        float4 w3 = *(const float4*)(wrow + 1536);
        #define KV_FMA(ri, A) \
            acc[ri][0] += A.x*w0.x + A.y*w1.x + A.z*w2.x + A.w*w3.x; \
            acc[ri][1] += A.x*w0.y + A.y*w1.y + A.z*w2.y + A.w*w3.y; \
            acc[ri][2] += A.x*w0.z + A.y*w1.z + A.z*w2.z + A.w*w3.z; \
            acc[ri][3] += A.x*w0.w + A.y*w1.w + A.z*w2.w + A.w*w3.w;
        KV_FMA(0, a0) KV_FMA(1, a1) KV_FMA(2, a2) KV_FMA(3, a3)
        #undef KV_FMA
    }
    // reduce k-quarters via LDS (reuse As after sync)
    __syncthreads();
    float* red = As;   // 256 threads * 16 floats = 4096 floats (fits in 8192)
    #pragma unroll
    for (int ri = 0; ri < 4; ++ri)
        *(float4*)(red + ((rq4*4+ri)*16 + cq)*16 + kq*4) =
            make_float4(acc[ri][0], acc[ri][1], acc[ri][2], acc[ri][3]);
    __syncthreads();
    // 256 threads finalize 16x64 outputs (each thread: one row-quad? -> one (row, col4))
    {
        int c4 = tid & 15, row = tid >> 4;   // 16 rows x 16 col-quads
        float4 b4v = *(const float4*)(bias + colbase + c4*4);
        float o[4] = {b4v.x, b4v.y, b4v.z, b4v.w};
        #pragma unroll
        for (int kq2 = 0; kq2 < 4; ++kq2) {
            const float* pr = red + (row*16 + c4)*16 + kq2*4;
            o[0] += pr[0]; o[1] += pr[1]; o[2] += pr[2]; o[3] += pr[3];
        }
        *(float4*)(outp + (size_t)(rowbase + row)*512 + colbase + c4*4) =
            make_float4(o[0], o[1], o[2], o[3]);
    }
}

// Attention: 128 blocks = (b,h), 256 threads. qproj slice + scores + softmax + ctx.
__global__ __launch_bounds__(256) void attn_kernel(
        const float* __restrict__ emb, const float* __restrict__ Wq,
        const float* __restrict__ bq, float* __restrict__ ws, int t) {
    int b = blockIdx.x >> 3, h = blockIdx.x & 7;
    int tid = threadIdx.x;
    const float* hid = ws + ((t & 1) ? WS_HID1 : WS_HID0);
    unsigned long long* slots = (unsigned long long*)(ws + WS_SLOTS_F);
    __shared__ float q[2*HH];
    __shared__ float part[8*64];
    __shared__ float qh[64];
    __shared__ float sp[2*LL];
    __shared__ float p[LL];
    __shared__ float cpart[4*64];

    unsigned long long slot = slots[t*BB + b];
    unsigned idx = 0xFFFFFFFFu - (unsigned)(slot & 0xFFFFFFFFull);
    for (int i = tid; i < HH; i += 256) {
        q[i] = emb[(size_t)idx*HH + i];
        q[HH + i] = hid[b*HH + i];
    }
    __syncthreads();

    {   // qproj: thread = (c2 0..31 two cols, kc 0..7 k-slices of 128)
        int c2 = tid & 31, kc = tid >> 5;
        const float* wp = Wq + (size_t)(kc*128)*HH + h*64 + c2*2;
        const float* qp = q + kc*128;
        float a0 = 0.f, a1 = 0.f;
        #pragma unroll 8
        for (int kk = 0; kk < 128; ++kk) {
            float x = qp[kk];
            float2 w2 = *(const float2*)(wp + (size_t)kk*HH);
            a0 += x*w2.x; a1 += x*w2.y;
        }
        part[kc*64 + c2*2]     = a0;
        part[kc*64 + c2*2 + 1] = a1;
    }
    __syncthreads();
    if (tid < 64) {
        float s = bq[h*64 + tid];
        #pragma unroll
        for (int kc = 0; kc < 8; ++kc) s += part[kc*64 + tid];
        qh[tid] = s;
    }
    __syncthreads();

    {   // scores: thread = (l 0..127, jh 0..1)
        int l = tid & 127, jh = tid >> 7;
        const float4* kr = (const float4*)(ws + WS_K + ((size_t)(l*BB + b))*HH + h*DK) + jh*8;
        const float4* q4 = (const float4*)qh + jh*8;
        float acc = 0.f;
        #pragma unroll
        for (int j = 0; j < 8; ++j) {
            float4 kv = kr[j], qq = q4[j];
            acc += qq.x*kv.x + qq.y*kv.y + qq.z*kv.z + qq.w*kv.w;
        }
        sp[jh*128 + l] = acc;
    }
    __syncthreads();

    if (tid < 64) {   // softmax over 128 by wave 0
        float s0 = (sp[tid]      + sp[128 + tid])      * 0.125f;
        float s1 = (sp[64 + tid] + sp[192 + 64 + tid - 64]) * 0.125f;  // sp[192+tid]
        s1 = (sp[64 + tid] + sp[192 + tid]) * 0.125f;
        float m = fmaxf(s0, s1);
        #pragma unroll
        for (int off = 32; off; off >>= 1) m = fmaxf(m, __shfl_xor(m, off));
        float e0 = expf(s0 - m), e1 = expf(s1 - m);
        float sum = e0 + e1;
        #pragma unroll
        for (int off = 32; off; off >>= 1) sum += __shfl_xor(sum, off);
        float inv = 1.f / sum;
        p[tid]      = e0 * inv;
        p[64 + tid] = e1 * inv;
    }
    __syncthreads();
    if (tid < 128) ws[WS_P + (size_t)(b*NH + h)*LL + tid] = p[tid];

    {   // ctx: thread = (c 0..63, lc 0..3 l-slices of 32)
        int c = tid & 63, lc = tid >> 6;
        const float* Vp = ws + WS_V + h*DK + c;
        float acc = 0.f;
        #pragma unroll 8
        for (int li = 0; li < 32; ++li) {
            int l = lc*32 + li;
            acc += p[l] * Vp[(size_t)(l*BB + b)*HH];
        }
        cpart[lc*64 + c] = acc;
    }
    __syncthreads();
    if (tid < 64)
        ws[WS_CTX + b*HH + h*DK + tid] =
            cpart[tid] + cpart[64+tid] + cpart[128+tid] + cpart[192+tid];
}

// GRU gate pre-activations: 96 blocks = 6 gate-matrices x 16 col-slices(32).
// Weights read ONCE per step; all 16 batches from LDS. gcb==0 blocks also write sc.
__global__ __launch_bounds__(512) void gates_kernel(
        const float* __restrict__ Wih, const float* __restrict__ Whh,
        const int* __restrict__ olen, float* __restrict__ ws,
        float* __restrict__ out, int t) {
    int blk = blockIdx.x;
    int gcb = blk >> 4, cb = blk & 15;   // gcb 0..5, cb 0..15
    int tid = threadIdx.x;
    const float* hid = ws + ((t & 1) ? WS_HID1 : WS_HID0);
    int g = gcb - (gcb >= 3 ? 3 : 0);
    const float* W = (gcb >= 3) ? Whh : Wih;
    const float* src = (gcb >= 3) ? hid : (ws + WS_CTX);
    __shared__ float xs[512*20];      // [k][b] padded stride 20
    __shared__ float part[16*512];    // [kc][b*32+c]

    for (int i = tid; i < BB*HH; i += 512) {
        int bb = i >> 9, k = i & 511;
        xs[k*20 + bb] = src[i];
    }
    if (gcb == 0 && tid < 128) {   // sc output for batch cb (mean over heads)
        float s = 0.f;
        #pragma unroll
        for (int hh = 0; hh < NH; ++hh)
            s += ws[WS_P + (size_t)(cb*NH + hh)*LL + tid];
        bool active = t < olen[cb];
        out[OUT_SC_OFF + ((size_t)t*BB + cb)*LL + tid] = active ? s*0.125f : 0.f;
    }
    __syncthreads();

    int c4 = tid & 7, b4 = (tid >> 3) & 3, kc = tid >> 5;  // 8 x 4 x 16
    const float* wp = W + (size_t)g*HH + cb*32 + c4*4;
    float acc[4][4];
    #pragma unroll
    for (int i = 0; i < 4; ++i) { acc[i][0]=0.f; acc[i][1]=0.f; acc[i][2]=0.f; acc[i][3]=0.f; }
    #pragma unroll 4
    for (int kk = 0; kk < 32; ++kk) {
        int k = kc*32 + kk;
        float4 w4 = *(const float4*)(wp + (size_t)k*(3*HH));
        float4 x4 = *(const float4*)(xs + k*20 + b4*4);
        acc[0][0] += x4.x*w4.x; acc[0][1] += x4.x*w4.y; acc[0][2] += x4.x*w4.z; acc[0][3] += x4.x*w4.w;
        acc[1][0] += x4.y*w4.x; acc[1][1] += x4.y*w4.y; acc[1][2] += x4.y*w4.z; acc[1][3] += x4.y*w4.w;
        acc[2][0] += x4.z*w4.x; acc[2][1] += x4.z*w4.y; acc[2][2] += x4.z*w4.z; acc[2][3] += x4.z*w4.w;
        acc[3][0] += x4.w*w4.x; acc[3][1] += x4.w*w4.y; acc[3][2] += x4.w*w4.z; acc[3][3] += x4.w*w4.w;
    }
    #pragma unroll
    for (int bi = 0; bi < 4; ++bi)
        *(float4*)(part + kc*512 + (b4*4+bi)*32 + c4*4) =
            make_float4(acc[bi][0], acc[bi][1], acc[bi][2], acc[bi][3]);
    __syncthreads();
    {
        int e = tid;   // 512 outputs: b = e>>5, c = e&31
        float s = 0.f;
        #pragma unroll
        for (int kc2 = 0; kc2 < 16; ++kc2) s += part[kc2*512 + e];
        int bb = e >> 5, cc = e & 31;
        ws[WS_G + (size_t)gcb*BB*HH + bb*HH + cb*32 + cc] = s;
    }
}

// Logits + fused GRU finalize + fused argmax. 250 blocks x 256.
__global__ __launch_bounds__(256) void logits_kernel(
        const float* __restrict__ Wf, const float* __restrict__ bf,
        const float* __restrict__ bih, const float* __restrict__ bhh,
        const int* __restrict__ olen, float* __restrict__ ws,
        float* __restrict__ out, int t) {
    __shared__ float hs[BB*HH];
    __shared__ unsigned long long am[BB*64];
    int tid = threadIdx.x;
    const float* hold = ws + ((t & 1) ? WS_HID1 : WS_HID0);
    float* hnew_ws = ws + ((t & 1) ? WS_HID0 : WS_HID1);
    const float* gp = ws + WS_G;

    for (int i = tid; i < BB*HH; i += 256) {   // GRU finalize (redundant per block)
        int c = i & 511;
        float gir = gp[i],            giz = gp[BB*HH + i],   gin = gp[2*BB*HH + i];
        float ghr = gp[3*BB*HH + i],  ghz = gp[4*BB*HH + i],  ghn = gp[5*BB*HH + i];
        float r = 1.f/(1.f + expf(-(gir + bih[c]       + ghr + bhh[c])));
        float z = 1.f/(1.f + expf(-(giz + bih[512 + c] + ghz + bhh[512 + c])));
        float n = tanhf(gin + bih[1024 + c] + r*(ghn + bhh[1024 + c]));
        float hv = hold[i];
        float hn2 = (1.f - z)*n + z*hv;
        hs[i] = hn2;
        if (blockIdx.x == 0) {
            hnew_ws[i] = hn2;                          // carry (unmasked)
            int bb = i >> 9;
            out[OUT_HID_OFF + ((size_t)t*BB + bb)*HH + c] = (t < olen[bb]) ? hn2 : 0.f;
        }
    }
    __syncthreads();

    int colLocal = tid & 63, bg = tid >> 6;
    int col = blockIdx.x*64 + colLocal;
    const float* h0 = hs + (bg*4+0)*HH;
    const float* h1 = hs + (bg*4+1)*HH;
    const float* h2 = hs + (bg*4+2)*HH;
    const float* h3 = hs + (bg*4+3)*HH;
    float a0=0.f, a1=0.f, a2=0.f, a3=0.f;
    const float* wp = Wf + col;
    #pragma unroll 4
    for (int k = 0; k < HH; k += 4) {
        float wv0 = wp[(size_t)(k+0)*VV];
        float wv1 = wp[(size_t)(k+1)*VV];
        float wv2 = wp[(size_t)(k+2)*VV];
        float wv3 = wp[(size_t)(k+3)*VV];
        float4 hv0 = *(const float4*)(h0 + k);
        float4 hv1 = *(const float4*)(h1 + k);
        float4 hv2 = *(const float4*)(h2 + k);
        float4 hv3 = *(const float4*)(h3 + k);
        a0 += wv0*hv0.x + wv1*hv0.y + wv2*hv0.z + wv3*hv0.w;
        a1 += wv0*hv1.x + wv1*hv1.y + wv2*hv1.z + wv3*hv1.w;
        a2 += wv0*hv2.x + wv1*hv2.y + wv2*hv2.z + wv3*hv2.w;
        a3 += wv0*hv3.x + wv1*hv3.y + wv2*hv3.z + wv3*hv3.w;
    }
    float bfc = bf[col];
    float vals[4] = {a0+bfc, a1+bfc, a2+bfc, a3+bfc};
    #pragma unroll
    for (int j = 0; j < 4; ++j) {
        int b = bg*4 + j;
        bool active = t < olen[b];
        out[((size_t)t*BB + b)*VV + col] = active ? vals[j] : 0.f;
        unsigned u = __float_as_uint(vals[j]);
        u = (u & 0x80000000u) ? ~u : (u | 0x80000000u);
        am[b*64 + colLocal] = ((unsigned long long)u << 32)
                            | (unsigned long long)(0xFFFFFFFFu - (unsigned)col);
    }
    __syncthreads();
    if (tid < BB) {
        unsigned long long m = 0ull;
        #pragma unroll 8
        for (int i = 0; i < 64; ++i) {
            unsigned long long v = am[tid*64 + i];
            m = v > m ? v : m;
        }
        unsigned long long* slots = (unsigned long long*)(ws + WS_SLOTS_F);
        atomicMax(&slots[(size_t)(t+1)*BB + tid], m);
    }
}

extern "C" void kernel_launch(void* const* d_in, const int* in_sizes, int n_in,
                              void* d_out, int out_size, void* d_ws, size_t ws_size,
                              hipStream_t stream) {
    const float* mem = (const float*)d_in[0];
    const float* emb = (const float*)d_in[1];
    const float* Wq  = (const float*)d_in[2];
    const float* bq  = (const float*)d_in[3];
    const float* Wk  = (const float*)d_in[4];
    const float* bk  = (const float*)d_in[5];
    const float* Wv  = (const float*)d_in[6];
    const float* bv  = (const float*)d_in[7];
    const float* Wih = (const float*)d_in[8];
    const float* bih = (const float*)d_in[9];
    const float* Whh = (const float*)d_in[10];
    const float* bhh = (const float*)d_in[11];
    const float* Wf  = (const float*)d_in[12];
    const float* bf  = (const float*)d_in[13];
    const int* olen  = (const int*)d_in[14];
    float* out = (float*)d_out;
    float* ws  = (float*)d_ws;

    hipLaunchKernelGGL(kv_kernel, dim3(2048), dim3(256), 0, stream, mem, Wk, bk, Wv, bv, ws);
    for (int t = 0; t < TT; ++t) {
        hipLaunchKernelGGL(attn_kernel, dim3(BB*NH), dim3(256), 0, stream, emb, Wq, bq, ws, t);
        hipLaunchKernelGGL(gates_kernel, dim3(96), dim3(512), 0, stream, Wih, Whh, olen, ws, out, t);
        hipLaunchKernelGGL(logits_kernel, dim3(250), dim3(256), 0, stream,
                           Wf, bf, bih, bhh, olen, ws, out, t);
    }
}

// Round 3
// 1537.900 us; speedup vs baseline: 1.9102x; 1.3289x over previous
//
#include <hip/hip_runtime.h>

#define LL 128      // memory length
#define BB 16       // batch
#define HH 512      // hidden
#define VV 16000    // vocab
#define TT 32       // steps
#define NH 8        // heads
#define DK 64       // head dim

// workspace layout (float offsets)
#define WS_K 0
#define WS_V (LL*BB*HH)
#define WS_HID0 (2*LL*BB*HH)
#define WS_HID1 (WS_HID0 + BB*HH)
#define WS_CTX  (WS_HID1 + BB*HH)
#define WS_P    (WS_CTX + BB*HH)          // p[b][h][128]
#define WS_G    (WS_P + BB*NH*LL)         // gates[6][b][512] (pre-bias)
#define WS_SLOTS_F (WS_G + 6*BB*HH)       // uint64 argmax slots (8B aligned)

#define OUT_HID_OFF ((size_t)TT*BB*VV)
#define OUT_SC_OFF  (OUT_HID_OFF + (size_t)TT*BB*HH)

// slots[t*BB+b]: hi32 = monotonic float encoding, lo32 = 0xFFFFFFFF - col
// atomicMax -> max value, tie -> smallest col (jnp.argmax first occurrence)

// K|V projection: grid 2048 = 128 rowgroups(16 rows) x 16 coltiles(64 cols over K|V).
// Block 0 additionally does the per-call init (hid0 zero, argmax slots).
__global__ __launch_bounds__(256) void kv_kernel(const float* __restrict__ mem,
        const float* __restrict__ Wk, const float* __restrict__ bk,
        const float* __restrict__ Wv, const float* __restrict__ bv,
        float* __restrict__ ws) {
    int blk = blockIdx.x;
    int rg = blk >> 4, ct = blk & 15;
    int isV = ct >= 8;
    int colbase = (ct & 7) * 64;
    const float* W = isV ? Wv : Wk;
    const float* bias = isV ? bv : bk;
    float* outp = ws + (isV ? WS_V : WS_K);
    int rowbase = rg * 16;
    int tid = threadIdx.x;
    __shared__ float As[16*512];

    const float4* srcp = (const float4*)(mem + (size_t)rowbase*512);
    float4* dstp = (float4*)As;
    #pragma unroll
    for (int i = 0; i < 8; ++i) dstp[tid + 256*i] = srcp[tid + 256*i];

    if (blk == 0) {
        for (int i = tid; i < BB*HH; i += 256) ws[WS_HID0 + i] = 0.f;
        unsigned long long* slots = (unsigned long long*)(ws + WS_SLOTS_F);
        for (int i = tid; i < (TT+1)*BB; i += 256)
            slots[i] = (i < BB) ? 0xFFFFFFFFull : 0ull;   // step0 argmax(zeros)=0
    }
    __syncthreads();

    int cq = tid & 15;
    int rq4 = (tid >> 4) & 3;
    int kq = tid >> 6;                      // 0..3: k-quarter (128 k each)
    const float4* As4 = (const float4*)As;
    float acc[4][4];
    #pragma unroll
    for (int i = 0; i < 4; ++i) { acc[i][0]=0.f; acc[i][1]=0.f; acc[i][2]=0.f; acc[i][3]=0.f; }
    const float* wp = W + colbase + cq*4;
    for (int k4 = kq*32; k4 < kq*32 + 32; ++k4) {
        float4 a0 = As4[(rq4*4+0)*128 + k4];
        float4 a1 = As4[(rq4*4+1)*128 + k4];
        float4 a2 = As4[(rq4*4+2)*128 + k4];
        float4 a3 = As4[(rq4*4+3)*128 + k4];
        const float* wrow = wp + (size_t)(4*k4)*512;
        float4 w0 = *(const float4*)(wrow);
        float4 w1 = *(const float4*)(wrow + 512);
        float4 w2 = *(const float4*)(wrow + 1024);
        float4 w3 = *(const float4*)(wrow + 1536);
        #define KV_FMA(ri, A) \
            acc[ri][0] += A.x*w0.x + A.y*w1.x + A.z*w2.x + A.w*w3.x; \
            acc[ri][1] += A.x*w0.y + A.y*w1.y + A.z*w2.y + A.w*w3.y; \
            acc[ri][2] += A.x*w0.z + A.y*w1.z + A.z*w2.z + A.w*w3.z; \
            acc[ri][3] += A.x*w0.w + A.y*w1.w + A.z*w2.w + A.w*w3.w;
        KV_FMA(0, a0) KV_FMA(1, a1) KV_FMA(2, a2) KV_FMA(3, a3)
        #undef KV_FMA
    }
    __syncthreads();
    float* red = As;
    #pragma unroll
    for (int ri = 0; ri < 4; ++ri)
        *(float4*)(red + ((rq4*4+ri)*16 + cq)*16 + kq*4) =
            make_float4(acc[ri][0], acc[ri][1], acc[ri][2], acc[ri][3]);
    __syncthreads();
    {
        int c4 = tid & 15, row = tid >> 4;   // 16 rows x 16 col-quads
        float4 b4v = *(const float4*)(bias + colbase + c4*4);
        float o[4] = {b4v.x, b4v.y, b4v.z, b4v.w};
        #pragma unroll
        for (int kq2 = 0; kq2 < 4; ++kq2) {
            const float* pr = red + (row*16 + c4)*16 + kq2*4;
            o[0] += pr[0]; o[1] += pr[1]; o[2] += pr[2]; o[3] += pr[3];
        }
        *(float4*)(outp + (size_t)(rowbase + row)*512 + colbase + c4*4) =
            make_float4(o[0], o[1], o[2], o[3]);
    }
}

// Attention: 128 blocks = (b,h), 256 threads. qproj slice + scores + softmax + ctx.
__global__ __launch_bounds__(256) void attn_kernel(
        const float* __restrict__ emb, const float* __restrict__ Wq,
        const float* __restrict__ bq, float* __restrict__ ws, int t) {
    int b = blockIdx.x >> 3, h = blockIdx.x & 7;
    int tid = threadIdx.x;
    const float* hid = ws + ((t & 1) ? WS_HID1 : WS_HID0);
    unsigned long long* slots = (unsigned long long*)(ws + WS_SLOTS_F);
    __shared__ float q[2*HH];
    __shared__ float part[8*64];
    __shared__ float qh[64];
    __shared__ float sp[2*LL];
    __shared__ float p[LL];
    __shared__ float cpart[4*64];

    unsigned long long slot = slots[t*BB + b];
    unsigned idx = 0xFFFFFFFFu - (unsigned)(slot & 0xFFFFFFFFull);
    for (int i = tid; i < HH; i += 256) {
        q[i] = emb[(size_t)idx*HH + i];
        q[HH + i] = hid[b*HH + i];
    }
    __syncthreads();

    {   // qproj: thread = (c2 0..31 two cols, kc 0..7 k-slices of 128)
        int c2 = tid & 31, kc = tid >> 5;
        const float* wp = Wq + (size_t)(kc*128)*HH + h*64 + c2*2;
        const float* qp = q + kc*128;
        float a0 = 0.f, a1 = 0.f;
        #pragma unroll 8
        for (int kk = 0; kk < 128; ++kk) {
            float x = qp[kk];
            float2 w2 = *(const float2*)(wp + (size_t)kk*HH);
            a0 += x*w2.x; a1 += x*w2.y;
        }
        part[kc*64 + c2*2]     = a0;
        part[kc*64 + c2*2 + 1] = a1;
    }
    __syncthreads();
    if (tid < 64) {
        float s = bq[h*64 + tid];
        #pragma unroll
        for (int kc = 0; kc < 8; ++kc) s += part[kc*64 + tid];
        qh[tid] = s;
    }
    __syncthreads();

    {   // scores: thread = (l 0..127, jh 0..1)
        int l = tid & 127, jh = tid >> 7;
        const float4* kr = (const float4*)(ws + WS_K + ((size_t)(l*BB + b))*HH + h*DK) + jh*8;
        const float4* q4 = (const float4*)qh + jh*8;
        float acc = 0.f;
        #pragma unroll
        for (int j = 0; j < 8; ++j) {
            float4 kv = kr[j], qq = q4[j];
            acc += qq.x*kv.x + qq.y*kv.y + qq.z*kv.z + qq.w*kv.w;
        }
        sp[jh*128 + l] = acc;
    }
    __syncthreads();

    if (tid < 64) {   // softmax over 128 by wave 0
        float s0 = (sp[tid]      + sp[128 + tid]) * 0.125f;
        float s1 = (sp[64 + tid] + sp[192 + tid]) * 0.125f;
        float m = fmaxf(s0, s1);
        #pragma unroll
        for (int off = 32; off; off >>= 1) m = fmaxf(m, __shfl_xor(m, off));
        float e0 = expf(s0 - m), e1 = expf(s1 - m);
        float sum = e0 + e1;
        #pragma unroll
        for (int off = 32; off; off >>= 1) sum += __shfl_xor(sum, off);
        float inv = 1.f / sum;
        p[tid]      = e0 * inv;
        p[64 + tid] = e1 * inv;
    }
    __syncthreads();
    if (tid < 128) ws[WS_P + (size_t)(b*NH + h)*LL + tid] = p[tid];

    {   // ctx: thread = (c 0..63, lc 0..3 l-slices of 32)
        int c = tid & 63, lc = tid >> 6;
        const float* Vp = ws + WS_V + h*DK + c;
        float acc = 0.f;
        #pragma unroll 8
        for (int li = 0; li < 32; ++li) {
            int l = lc*32 + li;
            acc += p[l] * Vp[(size_t)(l*BB + b)*HH];
        }
        cpart[lc*64 + c] = acc;
    }
    __syncthreads();
    if (tid < 64)
        ws[WS_CTX + b*HH + h*DK + tid] =
            cpart[tid] + cpart[64+tid] + cpart[128+tid] + cpart[192+tid];
}

// GRU gate pre-activations: 96 blocks = 6 gate-matrices x 16 col-slices(32).
__global__ __launch_bounds__(512) void gates_kernel(
        const float* __restrict__ Wih, const float* __restrict__ Whh,
        const int* __restrict__ olen, float* __restrict__ ws,
        float* __restrict__ out, int t) {
    int blk = blockIdx.x;
    int gcb = blk >> 4, cb = blk & 15;   // gcb 0..5, cb 0..15
    int tid = threadIdx.x;
    const float* hid = ws + ((t & 1) ? WS_HID1 : WS_HID0);
    int g = gcb - (gcb >= 3 ? 3 : 0);
    const float* W = (gcb >= 3) ? Whh : Wih;
    const float* src = (gcb >= 3) ? hid : (ws + WS_CTX);
    __shared__ float xs[512*20];      // [k][b] padded stride 20
    __shared__ float part[16*512];    // [kc][b*32+c]

    for (int i = tid; i < BB*HH; i += 512) {
        int bb = i >> 9, k = i & 511;
        xs[k*20 + bb] = src[i];
    }
    if (gcb == 0 && tid < 128) {   // sc output for batch cb (mean over heads)
        float s = 0.f;
        #pragma unroll
        for (int hh = 0; hh < NH; ++hh)
            s += ws[WS_P + (size_t)(cb*NH + hh)*LL + tid];
        bool active = t < olen[cb];
        out[OUT_SC_OFF + ((size_t)t*BB + cb)*LL + tid] = active ? s*0.125f : 0.f;
    }
    __syncthreads();

    int c4 = tid & 7, b4 = (tid >> 3) & 3, kc = tid >> 5;  // 8 x 4 x 16
    const float* wp = W + (size_t)g*HH + cb*32 + c4*4;
    float acc[4][4];
    #pragma unroll
    for (int i = 0; i < 4; ++i) { acc[i][0]=0.f; acc[i][1]=0.f; acc[i][2]=0.f; acc[i][3]=0.f; }
    #pragma unroll 4
    for (int kk = 0; kk < 32; ++kk) {
        int k = kc*32 + kk;
        float4 w4 = *(const float4*)(wp + (size_t)k*(3*HH));
        float4 x4 = *(const float4*)(xs + k*20 + b4*4);
        acc[0][0] += x4.x*w4.x; acc[0][1] += x4.x*w4.y; acc[0][2] += x4.x*w4.z; acc[0][3] += x4.x*w4.w;
        acc[1][0] += x4.y*w4.x; acc[1][1] += x4.y*w4.y; acc[1][2] += x4.y*w4.z; acc[1][3] += x4.y*w4.w;
        acc[2][0] += x4.z*w4.x; acc[2][1] += x4.z*w4.y; acc[2][2] += x4.z*w4.z; acc[2][3] += x4.z*w4.w;
        acc[3][0] += x4.w*w4.x; acc[3][1] += x4.w*w4.y; acc[3][2] += x4.w*w4.z; acc[3][3] += x4.w*w4.w;
    }
    #pragma unroll
    for (int bi = 0; bi < 4; ++bi)
        *(float4*)(part + kc*512 + (b4*4+bi)*32 + c4*4) =
            make_float4(acc[bi][0], acc[bi][1], acc[bi][2], acc[bi][3]);
    __syncthreads();
    {
        int e = tid;   // 512 outputs: b = e>>5, c = e&31
        float s = 0.f;
        #pragma unroll
        for (int kc2 = 0; kc2 < 16; ++kc2) s += part[kc2*512 + e];
        int bb = e >> 5, cc = e & 31;
        ws[WS_G + (size_t)gcb*BB*HH + bb*HH + cb*32 + cc] = s;
    }
}

// Logits + fused GRU finalize + fused argmax. 250 blocks x 256.
// Thread = (kc: tid>>4, 16 interleaved k-slices) x (bh: (tid>>3)&1) x (c8: tid&7).
__global__ __launch_bounds__(256) void logits_kernel(
        const float* __restrict__ Wf, const float* __restrict__ bf,
        const float* __restrict__ bih, const float* __restrict__ bhh,
        const int* __restrict__ olen, float* __restrict__ ws,
        float* __restrict__ out, int t) {
    __shared__ float hs[HH*20];              // h_new in [k][b] layout, stride 20
    __shared__ float red2[4*1028];           // per-wave partials [w][b*64+c]
    __shared__ unsigned long long am[BB*16];
    int tid = threadIdx.x;
    const float* hold = ws + ((t & 1) ? WS_HID1 : WS_HID0);
    float* hnew_ws = ws + ((t & 1) ? WS_HID0 : WS_HID1);
    const float* gp = ws + WS_G;

    // ---- GRU finalize (redundant per block, fast-math): units = (c, b-quad)
    #pragma unroll 2
    for (int jj = 0; jj < 8; ++jj) {
        int u = tid + 256*jj;
        int c = u & 511, bq = u >> 9;
        float hv[4];
        #pragma unroll
        for (int i = 0; i < 4; ++i) {
            int b = bq*4 + i;
            int e = b*HH + c;
            float gir = gp[e],            giz = gp[BB*HH + e],   gin = gp[2*BB*HH + e];
            float ghr = gp[3*BB*HH + e],  ghz = gp[4*BB*HH + e],  ghn = gp[5*BB*HH + e];
            float xr = gir + bih[c]        + ghr + bhh[c];
            float xz = giz + bih[HH + c]   + ghz + bhh[HH + c];
            float r = 1.f/(1.f + __expf(-xr));
            float z = 1.f/(1.f + __expf(-xz));
            float xn = gin + bih[2*HH + c] + r*(ghn + bhh[2*HH + c]);
            float n = 1.f - 2.f/(__expf(2.f*xn) + 1.f);
            float h0 = hold[e];
            float hn2 = (1.f - z)*n + z*h0;
            hv[i] = hn2;
            if (blockIdx.x == 0) {
                hnew_ws[e] = hn2;                              // carry (unmasked)
                out[OUT_HID_OFF + ((size_t)t*BB + b)*HH + c] = (t < olen[b]) ? hn2 : 0.f;
            }
        }
        *(float4*)(hs + c*20 + bq*4) = make_float4(hv[0], hv[1], hv[2], hv[3]);
    }
    __syncthreads();

    // ---- GEMM: 64 cols x 16 b x 512 k
    int c8 = tid & 7, bh = (tid >> 3) & 1, kc = tid >> 4;
    int colbase = blockIdx.x * 64;
    float acc[8][8];
    #pragma unroll
    for (int bi = 0; bi < 8; ++bi)
        #pragma unroll
        for (int ci = 0; ci < 8; ++ci) acc[bi][ci] = 0.f;
    const float* wp = Wf + (size_t)kc*VV + colbase + c8*8;
    const float* hp = hs + kc*20 + bh*8;
    #pragma unroll 4
    for (int i = 0; i < 32; ++i) {
        float4 w0 = *(const float4*)(wp);
        float4 w1 = *(const float4*)(wp + 4);
        float4 ha = *(const float4*)(hp);
        float4 hb = *(const float4*)(hp + 4);
        wp += (size_t)16 * VV;
        hp += 16 * 20;
        #define LG_ROW(bi, hc) \
            acc[bi][0] += hc*w0.x; acc[bi][1] += hc*w0.y; acc[bi][2] += hc*w0.z; acc[bi][3] += hc*w0.w; \
            acc[bi][4] += hc*w1.x; acc[bi][5] += hc*w1.y; acc[bi][6] += hc*w1.z; acc[bi][7] += hc*w1.w;
        LG_ROW(0, ha.x) LG_ROW(1, ha.y) LG_ROW(2, ha.z) LG_ROW(3, ha.w)
        LG_ROW(4, hb.x) LG_ROW(5, hb.y) LG_ROW(6, hb.z) LG_ROW(7, hb.w)
        #undef LG_ROW
    }

    // ---- reduce kc within each wave via shuffles (4 kc per wave)
    #pragma unroll
    for (int bi = 0; bi < 8; ++bi)
        #pragma unroll
        for (int ci = 0; ci < 8; ++ci) {
            float v = acc[bi][ci];
            v += __shfl_xor(v, 16);
            v += __shfl_xor(v, 32);
            acc[bi][ci] = v;
        }
    int wv = tid >> 6;
    if (((tid >> 4) & 3) == 0) {   // one lane-set per wave holds the wave partial
        #pragma unroll
        for (int bi = 0; bi < 8; ++bi) {
            int b = bh*8 + bi;
            *(float4*)(red2 + wv*1028 + b*64 + c8*8) =
                make_float4(acc[bi][0], acc[bi][1], acc[bi][2], acc[bi][3]);
            *(float4*)(red2 + wv*1028 + b*64 + c8*8 + 4) =
                make_float4(acc[bi][4], acc[bi][5], acc[bi][6], acc[bi][7]);
        }
    }
    __syncthreads();

    // ---- final: 1024 outputs, thread = (b = tid>>4, c4 = (tid&15)*4)
    {
        int b = tid >> 4, c4 = (tid & 15) * 4;
        float4 s = *(const float4*)(bf + colbase + c4);
        #pragma unroll
        for (int w = 0; w < 4; ++w) {
            float4 r = *(const float4*)(red2 + w*1028 + b*64 + c4);
            s.x += r.x; s.y += r.y; s.z += r.z; s.w += r.w;
        }
        bool active = t < olen[b];
        float4 outv;
        outv.x = active ? s.x : 0.f; outv.y = active ? s.y : 0.f;
        outv.z = active ? s.z : 0.f; outv.w = active ? s.w : 0.f;
        *(float4*)(out + ((size_t)t*BB + b)*VV + colbase + c4) = outv;

        float vals[4] = {s.x, s.y, s.z, s.w};
        unsigned long long m = 0ull;
        #pragma unroll
        for (int j = 0; j < 4; ++j) {
            unsigned u = __float_as_uint(vals[j]);
            u = (u & 0x80000000u) ? ~u : (u | 0x80000000u);
            unsigned col = (unsigned)(colbase + c4 + j);
            unsigned long long e = ((unsigned long long)u << 32)
                                 | (unsigned long long)(0xFFFFFFFFu - col);
            m = e > m ? e : m;
        }
        am[b*16 + (tid & 15)] = m;
    }
    __syncthreads();
    if (tid < BB) {
        unsigned long long m = 0ull;
        #pragma unroll
        for (int i = 0; i < 16; ++i) {
            unsigned long long v = am[tid*16 + i];
            m = v > m ? v : m;
        }
        unsigned long long* slots = (unsigned long long*)(ws + WS_SLOTS_F);
        atomicMax(&slots[(size_t)(t+1)*BB + tid], m);
    }
}

extern "C" void kernel_launch(void* const* d_in, const int* in_sizes, int n_in,
                              void* d_out, int out_size, void* d_ws, size_t ws_size,
                              hipStream_t stream) {
    const float* mem = (const float*)d_in[0];
    const float* emb = (const float*)d_in[1];
    const float* Wq  = (const float*)d_in[2];
    const float* bq  = (const float*)d_in[3];
    const float* Wk  = (const float*)d_in[4];
    const float* bk  = (const float*)d_in[5];
    const float* Wv  = (const float*)d_in[6];
    const float* bv  = (const float*)d_in[7];
    const float* Wih = (const float*)d_in[8];
    const float* bih = (const float*)d_in[9];
    const float* Whh = (const float*)d_in[10];
    const float* bhh = (const float*)d_in[11];
    const float* Wf  = (const float*)d_in[12];
    const float* bf  = (const float*)d_in[13];
    const int* olen  = (const int*)d_in[14];
    float* out = (float*)d_out;
    float* ws  = (float*)d_ws;

    hipLaunchKernelGGL(kv_kernel, dim3(2048), dim3(256), 0, stream, mem, Wk, bk, Wv, bv, ws);
    for (int t = 0; t < TT; ++t) {
        hipLaunchKernelGGL(attn_kernel, dim3(BB*NH), dim3(256), 0, stream, emb, Wq, bq, ws, t);
        hipLaunchKernelGGL(gates_kernel, dim3(96), dim3(512), 0, stream, Wih, Whh, olen, ws, out, t);
        hipLaunchKernelGGL(logits_kernel, dim3(250), dim3(256), 0, stream,
                           Wf, bf, bih, bhh, olen, ws, out, t);
    }
}

// Round 4
// 1463.306 us; speedup vs baseline: 2.0076x; 1.0510x over previous
//
#include <hip/hip_runtime.h>

#define LL 128      // memory length
#define BB 16       // batch
#define HH 512      // hidden
#define VV 16000    // vocab
#define TT 32       // steps
#define NH 8        // heads
#define DK 64       // head dim

// workspace layout (float offsets)
#define WS_K 0
#define WS_V (LL*BB*HH)
#define WS_HID0 (2*LL*BB*HH)
#define WS_HID1 (WS_HID0 + BB*HH)
#define WS_CTX  (WS_HID1 + BB*HH)
#define WS_P    (WS_CTX + BB*HH)          // p[b][h][128]
#define WS_HS   (WS_P + BB*NH*LL)         // h_new in [k][b] layout (512*16)
#define WS_SLOTS_F (WS_HS + 6*BB*HH)      // uint64 argmax slots (8B aligned)

#define OUT_HID_OFF ((size_t)TT*BB*VV)
#define OUT_SC_OFF  (OUT_HID_OFF + (size_t)TT*BB*HH)

// slots[t*BB+b]: hi32 = monotonic float encoding, lo32 = 0xFFFFFFFF - col
// atomicMax -> max value, tie -> smallest col (jnp.argmax first occurrence)

// K|V projection: grid 2048 = 128 rowgroups(16 rows) x 16 coltiles(64 cols over K|V).
// Block 0 additionally does the per-call init (hid0 zero, argmax slots).
// A-tile LDS padded to stride 516 (bank rotation: row*516 % 32 = row*4).
__global__ __launch_bounds__(256) void kv_kernel(const float* __restrict__ mem,
        const float* __restrict__ Wk, const float* __restrict__ bk,
        const float* __restrict__ Wv, const float* __restrict__ bv,
        float* __restrict__ ws) {
    int blk = blockIdx.x;
    int rg = blk >> 4, ct = blk & 15;
    int isV = ct >= 8;
    int colbase = (ct & 7) * 64;
    const float* W = isV ? Wv : Wk;
    const float* bias = isV ? bv : bk;
    float* outp = ws + (isV ? WS_V : WS_K);
    int rowbase = rg * 16;
    int tid = threadIdx.x;
    __shared__ float As[16*516];

    {   // stage 16x512 A rows into padded LDS
        const float4* srcp = (const float4*)(mem + (size_t)rowbase*512);
        #pragma unroll
        for (int j = 0; j < 8; ++j) {
            int i = tid + 256*j;            // 2048 float4
            float4 v = srcp[i];
            int row = i >> 7, c4i = i & 127;
            *(float4*)(As + row*516 + c4i*4) = v;
        }
    }
    if (blk == 0) {
        for (int i = tid; i < BB*HH; i += 256) ws[WS_HID0 + i] = 0.f;
        unsigned long long* slots = (unsigned long long*)(ws + WS_SLOTS_F);
        for (int i = tid; i < (TT+1)*BB; i += 256)
            slots[i] = (i < BB) ? 0xFFFFFFFFull : 0ull;   // step0 argmax(zeros)=0
    }
    __syncthreads();

    int cq = tid & 15;
    int rq4 = (tid >> 4) & 3;
    int kq = tid >> 6;                      // 0..3: k-quarter (128 k each)
    float acc[4][4];
    #pragma unroll
    for (int i = 0; i < 4; ++i) { acc[i][0]=0.f; acc[i][1]=0.f; acc[i][2]=0.f; acc[i][3]=0.f; }
    const float* wp = W + colbase + cq*4;
    for (int k4 = kq*32; k4 < kq*32 + 32; ++k4) {
        float4 a0 = *(const float4*)(As + (rq4*4+0)*516 + k4*4);
        float4 a1 = *(const float4*)(As + (rq4*4+1)*516 + k4*4);
        float4 a2 = *(const float4*)(As + (rq4*4+2)*516 + k4*4);
        float4 a3 = *(const float4*)(As + (rq4*4+3)*516 + k4*4);
        const float* wrow = wp + (size_t)(4*k4)*512;
        float4 w0 = *(const float4*)(wrow);
        float4 w1 = *(const float4*)(wrow + 512);
        float4 w2 = *(const float4*)(wrow + 1024);
        float4 w3 = *(const float4*)(wrow + 1536);
        #define KV_FMA(ri, A) \
            acc[ri][0] += A.x*w0.x + A.y*w1.x + A.z*w2.x + A.w*w3.x; \
            acc[ri][1] += A.x*w0.y + A.y*w1.y + A.z*w2.y + A.w*w3.y; \
            acc[ri][2] += A.x*w0.z + A.y*w1.z + A.z*w2.z + A.w*w3.z; \
            acc[ri][3] += A.x*w0.w + A.y*w1.w + A.z*w2.w + A.w*w3.w;
        KV_FMA(0, a0) KV_FMA(1, a1) KV_FMA(2, a2) KV_FMA(3, a3)
        #undef KV_FMA
    }
    __syncthreads();
    // reduce k-quarters: red[ri][tid] float4, lane-contiguous writes (reuse As)
    float* red = As;
    #pragma unroll
    for (int ri = 0; ri < 4; ++ri)
        *(float4*)(red + ri*1024 + tid*4) =
            make_float4(acc[ri][0], acc[ri][1], acc[ri][2], acc[ri][3]);
    __syncthreads();
    {
        int c4 = tid & 15, row = tid >> 4;   // 16 rows x 16 col-quads
        int rq = row >> 2, ri = row & 3;
        float4 b4v = *(const float4*)(bias + colbase + c4*4);
        float o[4] = {b4v.x, b4v.y, b4v.z, b4v.w};
        #pragma unroll
        for (int kq2 = 0; kq2 < 4; ++kq2) {
            const float* pr = red + ri*1024 + (kq2*64 + rq*16 + c4)*4;
            o[0] += pr[0]; o[1] += pr[1]; o[2] += pr[2]; o[3] += pr[3];
        }
        *(float4*)(outp + (size_t)(rowbase + row)*512 + colbase + c4*4) =
            make_float4(o[0], o[1], o[2], o[3]);
    }
}

// Attention: 128 blocks = (b,h), 256 threads. qproj slice + scores + softmax + ctx.
__global__ __launch_bounds__(256) void attn_kernel(
        const float* __restrict__ emb, const float* __restrict__ Wq,
        const float* __restrict__ bq, float* __restrict__ ws, int t) {
    int b = blockIdx.x >> 3, h = blockIdx.x & 7;
    int tid = threadIdx.x;
    const float* hid = ws + ((t & 1) ? WS_HID1 : WS_HID0);
    unsigned long long* slots = (unsigned long long*)(ws + WS_SLOTS_F);
    __shared__ float q[2*HH];
    __shared__ float part[8*64];
    __shared__ float qh[64];
    __shared__ float sp[2*LL];
    __shared__ float p[LL];
    __shared__ float cpart[4*64];

    unsigned long long slot = slots[t*BB + b];
    unsigned idx = 0xFFFFFFFFu - (unsigned)(slot & 0xFFFFFFFFull);
    for (int i = tid; i < HH; i += 256) {
        q[i] = emb[(size_t)idx*HH + i];
        q[HH + i] = hid[b*HH + i];
    }
    __syncthreads();

    {   // qproj: thread = (c2 0..31 two cols, kc 0..7 k-slices of 128)
        int c2 = tid & 31, kc = tid >> 5;
        const float* wp = Wq + (size_t)(kc*128)*HH + h*64 + c2*2;
        const float* qp = q + kc*128;
        float a0 = 0.f, a1 = 0.f;
        #pragma unroll 8
        for (int kk = 0; kk < 128; ++kk) {
            float x = qp[kk];
            float2 w2 = *(const float2*)(wp + (size_t)kk*HH);
            a0 += x*w2.x; a1 += x*w2.y;
        }
        part[kc*64 + c2*2]     = a0;
        part[kc*64 + c2*2 + 1] = a1;
    }
    __syncthreads();
    if (tid < 64) {
        float s = bq[h*64 + tid];
        #pragma unroll
        for (int kc = 0; kc < 8; ++kc) s += part[kc*64 + tid];
        qh[tid] = s;
    }
    __syncthreads();

    {   // scores: thread = (l 0..127, jh 0..1)
        int l = tid & 127, jh = tid >> 7;
        const float4* kr = (const float4*)(ws + WS_K + ((size_t)(l*BB + b))*HH + h*DK) + jh*8;
        const float4* q4 = (const float4*)qh + jh*8;
        float acc = 0.f;
        #pragma unroll
        for (int j = 0; j < 8; ++j) {
            float4 kv = kr[j], qq = q4[j];
            acc += qq.x*kv.x + qq.y*kv.y + qq.z*kv.z + qq.w*kv.w;
        }
        sp[jh*128 + l] = acc;
    }
    __syncthreads();

    if (tid < 64) {   // softmax over 128 by wave 0
        float s0 = (sp[tid]      + sp[128 + tid]) * 0.125f;
        float s1 = (sp[64 + tid] + sp[192 + tid]) * 0.125f;
        float m = fmaxf(s0, s1);
        #pragma unroll
        for (int off = 32; off; off >>= 1) m = fmaxf(m, __shfl_xor(m, off));
        float e0 = expf(s0 - m), e1 = expf(s1 - m);
        float sum = e0 + e1;
        #pragma unroll
        for (int off = 32; off; off >>= 1) sum += __shfl_xor(sum, off);
        float inv = 1.f / sum;
        p[tid]      = e0 * inv;
        p[64 + tid] = e1 * inv;
    }
    __syncthreads();
    if (tid < 128) ws[WS_P + (size_t)(b*NH + h)*LL + tid] = p[tid];

    {   // ctx: thread = (c 0..63, lc 0..3 l-slices of 32)
        int c = tid & 63, lc = tid >> 6;
        const float* Vp = ws + WS_V + h*DK + c;
        float acc = 0.f;
        #pragma unroll 8
        for (int li = 0; li < 32; ++li) {
            int l = lc*32 + li;
            acc += p[l] * Vp[(size_t)(l*BB + b)*HH];
        }
        cpart[lc*64 + c] = acc;
    }
    __syncthreads();
    if (tid < 64)
        ws[WS_CTX + b*HH + h*DK + tid] =
            cpart[tid] + cpart[64+tid] + cpart[128+tid] + cpart[192+tid];
}

// GRU gates + finalize: 32 blocks x 512 thr. Block cb owns cols cb*16..+16 for
// ALL 6 gate-matrices -> block-local finalize. Also writes sc + hiddens outputs,
// h_new carry (ping-pong) and the [k][b] h-copy for logits.
__global__ __launch_bounds__(512) void gates_kernel(
        const float* __restrict__ Wih, const float* __restrict__ bih,
        const float* __restrict__ Whh, const float* __restrict__ bhh,
        const int* __restrict__ olen, float* __restrict__ ws,
        float* __restrict__ out, int t) {
    int cb = blockIdx.x;      // 0..31
    int tid = threadIdx.x;
    const float* hid_in = ws + ((t & 1) ? WS_HID1 : WS_HID0);
    float* hid_out = ws + ((t & 1) ? WS_HID0 : WS_HID1);
    const float* ctx = ws + WS_CTX;
    __shared__ float xs[512*20];      // ctx  [k][b] stride 20
    __shared__ float hh[512*20];      // hid  [k][b] stride 20
    __shared__ float part[8*256];
    __shared__ float gacc[6*256];

    for (int i = tid; i < BB*HH; i += 512) {
        int bb = i >> 9, k = i & 511;
        xs[k*20 + bb] = ctx[i];
        hh[k*20 + bb] = hid_in[i];
    }
    if (tid < 64) {   // sc output: 64 of 2048 (b,l) pairs per block
        int e = cb*64 + tid;
        int b = e >> 7, l = e & 127;
        float s = 0.f;
        #pragma unroll
        for (int hq = 0; hq < NH; ++hq)
            s += ws[WS_P + (size_t)(b*NH + hq)*LL + l];
        out[OUT_SC_OFF + ((size_t)t*BB + b)*LL + l] = (t < olen[b]) ? s*0.125f : 0.f;
    }
    __syncthreads();

    int c4 = tid & 3, b4 = (tid >> 2) & 3, kc = tid >> 4;  // 4 x 4 x 32
    int wv = tid >> 6;
    for (int g = 0; g < 6; ++g) {
        const float* W = (g < 3) ? Wih : Whh;
        int gg = (g < 3) ? g : g - 3;
        const float* xsrc = (g < 3) ? xs : hh;
        const float* wp = W + (size_t)kc*(3*HH) + gg*HH + cb*16 + c4*4;
        const float* xp = xsrc + kc*20 + b4*4;
        float acc[4][4];
        #pragma unroll
        for (int i = 0; i < 4; ++i) { acc[i][0]=0.f; acc[i][1]=0.f; acc[i][2]=0.f; acc[i][3]=0.f; }
        #pragma unroll 8
        for (int i = 0; i < 16; ++i) {     // k = kc + 32*i
            float4 w4 = *(const float4*)wp;
            float4 x4 = *(const float4*)xp;
            wp += (size_t)32*(3*HH);
            xp += 32*20;
            acc[0][0] += x4.x*w4.x; acc[0][1] += x4.x*w4.y; acc[0][2] += x4.x*w4.z; acc[0][3] += x4.x*w4.w;
            acc[1][0] += x4.y*w4.x; acc[1][1] += x4.y*w4.y; acc[1][2] += x4.y*w4.z; acc[1][3] += x4.y*w4.w;
            acc[2][0] += x4.z*w4.x; acc[2][1] += x4.z*w4.y; acc[2][2] += x4.z*w4.z; acc[2][3] += x4.z*w4.w;
            acc[3][0] += x4.w*w4.x; acc[3][1] += x4.w*w4.y; acc[3][2] += x4.w*w4.z; acc[3][3] += x4.w*w4.w;
        }
        // in-wave reduce over kc bits (lane bits 4,5)
        #pragma unroll
        for (int bi = 0; bi < 4; ++bi)
            #pragma unroll
            for (int ci = 0; ci < 4; ++ci) {
                float v = acc[bi][ci];
                v += __shfl_xor(v, 16);
                v += __shfl_xor(v, 32);
                acc[bi][ci] = v;
            }
        if ((tid & 48) == 0) {   // lanes 0..15 of each wave hold (c4,b4) partial
            #pragma unroll
            for (int bi = 0; bi < 4; ++bi)
                *(float4*)(part + wv*256 + (b4*4+bi)*16 + c4*4) =
                    make_float4(acc[bi][0], acc[bi][1], acc[bi][2], acc[bi][3]);
        }
        __syncthreads();
        if (tid < 256) {
            int b = tid >> 4, c = tid & 15;
            float s = 0.f;
            #pragma unroll
            for (int w = 0; w < 8; ++w) s += part[w*256 + b*16 + c];
            gacc[g*256 + b*16 + c] = s;
        }
        __syncthreads();
    }

    // finalize: 256 threads, one (b, c) each
    if (tid < 256) {
        int b = tid >> 4, c = tid & 15;
        int col = cb*16 + c;
        float gir = gacc[0*256 + b*16 + c] + bih[col];
        float giz = gacc[1*256 + b*16 + c] + bih[HH + col];
        float gin = gacc[2*256 + b*16 + c] + bih[2*HH + col];
        float ghr = gacc[3*256 + b*16 + c] + bhh[col];
        float ghz = gacc[4*256 + b*16 + c] + bhh[HH + col];
        float ghn = gacc[5*256 + b*16 + c] + bhh[2*HH + col];
        float r = 1.f/(1.f + __expf(-(gir + ghr)));
        float z = 1.f/(1.f + __expf(-(giz + ghz)));
        float xn = gin + r*ghn;
        float n = 1.f - 2.f/(__expf(2.f*xn) + 1.f);
        float hprev = hh[col*20 + b];
        float hnew = (1.f - z)*n + z*hprev;
        hid_out[b*HH + col] = hnew;                                    // carry (unmasked)
        out[OUT_HID_OFF + ((size_t)t*BB + b)*HH + col] = (t < olen[b]) ? hnew : 0.f;
        ws[WS_HS + col*16 + b] = hnew;                                 // [k][b] for logits
    }
}

// Logits (pure GEMM) + fused argmax. 500 blocks x 256 thr, 32 cols/block.
// Thread = (c4: tid&7 col-quads, kc: tid>>3 k-slices); k = kc + 32*i (interleaved
// so stride-20 [k][b] LDS reads hit all 32 banks evenly).
__global__ __launch_bounds__(256) void logits_kernel(
        const float* __restrict__ Wf, const float* __restrict__ bf,
        const int* __restrict__ olen, float* __restrict__ ws,
        float* __restrict__ out, int t) {
    __shared__ float hs[HH*20];              // h_new [k][b], stride 20
    __shared__ float red[4*512];             // per-wave partials [w][b*32+c]
    __shared__ unsigned long long am[BB*16];
    int tid = threadIdx.x;

    {   // stage h from ws [512][16] -> padded LDS
        const float4* s4 = (const float4*)(ws + WS_HS);
        #pragma unroll
        for (int j = 0; j < 8; ++j) {
            int i = tid + 256*j;             // 2048 float4
            float4 v = s4[i];
            int row = i >> 2, qo = i & 3;
            *(float4*)(hs + row*20 + qo*4) = v;
        }
    }
    __syncthreads();

    int c4 = tid & 7, kc = tid >> 3;         // 8 col-quads, 32 k-slices
    int colbase = blockIdx.x * 32;
    float acc[16][4];
    #pragma unroll
    for (int bi = 0; bi < 16; ++bi) { acc[bi][0]=0.f; acc[bi][1]=0.f; acc[bi][2]=0.f; acc[bi][3]=0.f; }
    const float* wp = Wf + (size_t)kc*VV + colbase + c4*4;
    const float* hp = hs + kc*20;
    #pragma unroll 8
    for (int i = 0; i < 16; ++i) {           // k = kc + 32*i
        float4 w4 = *(const float4*)wp;
        float4 h0 = *(const float4*)(hp);
        float4 h1 = *(const float4*)(hp + 4);
        float4 h2 = *(const float4*)(hp + 8);
        float4 h3 = *(const float4*)(hp + 12);
        wp += (size_t)32 * VV;
        hp += 32 * 20;
        #define LACC(bi, hv) acc[bi][0] += (hv)*w4.x; acc[bi][1] += (hv)*w4.y; \
                             acc[bi][2] += (hv)*w4.z; acc[bi][3] += (hv)*w4.w;
        LACC(0,h0.x)  LACC(1,h0.y)  LACC(2,h0.z)  LACC(3,h0.w)
        LACC(4,h1.x)  LACC(5,h1.y)  LACC(6,h1.z)  LACC(7,h1.w)
        LACC(8,h2.x)  LACC(9,h2.y)  LACC(10,h2.z) LACC(11,h2.w)
        LACC(12,h3.x) LACC(13,h3.y) LACC(14,h3.z) LACC(15,h3.w)
        #undef LACC
    }

    // reduce over kc: in-wave lane bits 3,4,5
    #pragma unroll
    for (int bi = 0; bi < 16; ++bi)
        #pragma unroll
        for (int ci = 0; ci < 4; ++ci) {
            float v = acc[bi][ci];
            v += __shfl_xor(v, 8);
            v += __shfl_xor(v, 16);
            v += __shfl_xor(v, 32);
            acc[bi][ci] = v;
        }
    int wv = tid >> 6;
    if ((tid & 56) == 0) {   // lanes 0..7 (= c4) of each wave
        #pragma unroll
        for (int bi = 0; bi < 16; ++bi)
            *(float4*)(red + wv*512 + bi*32 + c4*4) =
                make_float4(acc[bi][0], acc[bi][1], acc[bi][2], acc[bi][3]);
    }
    __syncthreads();

    // final: 512 outputs (16b x 32c), 2 per thread
    {
        int b = tid >> 4, cp = (tid & 15) * 2;
        float2 bf2 = *(const float2*)(bf + colbase + cp);
        float v0 = bf2.x, v1 = bf2.y;
        #pragma unroll
        for (int w = 0; w < 4; ++w) {
            v0 += red[w*512 + b*32 + cp];
            v1 += red[w*512 + b*32 + cp + 1];
        }
        bool active = t < olen[b];
        float2 ov; ov.x = active ? v0 : 0.f; ov.y = active ? v1 : 0.f;
        *(float2*)(out + ((size_t)t*BB + b)*VV + colbase + cp) = ov;

        unsigned u0 = __float_as_uint(v0);
        u0 = (u0 & 0x80000000u) ? ~u0 : (u0 | 0x80000000u);
        unsigned u1 = __float_as_uint(v1);
        u1 = (u1 & 0x80000000u) ? ~u1 : (u1 | 0x80000000u);
        unsigned long long e0 = ((unsigned long long)u0 << 32)
                              | (unsigned long long)(0xFFFFFFFFu - (unsigned)(colbase + cp));
        unsigned long long e1 = ((unsigned long long)u1 << 32)
                              | (unsigned long long)(0xFFFFFFFFu - (unsigned)(colbase + cp + 1));
        am[b*16 + (tid & 15)] = e0 > e1 ? e0 : e1;
    }
    __syncthreads();
    if (tid < BB) {
        unsigned long long m = 0ull;
        #pragma unroll
        for (int i = 0; i < 16; ++i) {
            unsigned long long v = am[tid*16 + i];
            m = v > m ? v : m;
        }
        unsigned long long* slots = (unsigned long long*)(ws + WS_SLOTS_F);
        atomicMax(&slots[(size_t)(t+1)*BB + tid], m);
    }
}

extern "C" void kernel_launch(void* const* d_in, const int* in_sizes, int n_in,
                              void* d_out, int out_size, void* d_ws, size_t ws_size,
                              hipStream_t stream) {
    const float* mem = (const float*)d_in[0];
    const float* emb = (const float*)d_in[1];
    const float* Wq  = (const float*)d_in[2];
    const float* bq  = (const float*)d_in[3];
    const float* Wk  = (const float*)d_in[4];
    const float* bk  = (const float*)d_in[5];
    const float* Wv  = (const float*)d_in[6];
    const float* bv  = (const float*)d_in[7];
    const float* Wih = (const float*)d_in[8];
    const float* bih = (const float*)d_in[9];
    const float* Whh = (const float*)d_in[10];
    const float* bhh = (const float*)d_in[11];
    const float* Wf  = (const float*)d_in[12];
    const float* bf  = (const float*)d_in[13];
    const int* olen  = (const int*)d_in[14];
    float* out = (float*)d_out;
    float* ws  = (float*)d_ws;

    hipLaunchKernelGGL(kv_kernel, dim3(2048), dim3(256), 0, stream, mem, Wk, bk, Wv, bv, ws);
    for (int t = 0; t < TT; ++t) {
        hipLaunchKernelGGL(attn_kernel, dim3(BB*NH), dim3(256), 0, stream, emb, Wq, bq, ws, t);
        hipLaunchKernelGGL(gates_kernel, dim3(32), dim3(512), 0, stream,
                           Wih, bih, Whh, bhh, olen, ws, out, t);
        hipLaunchKernelGGL(logits_kernel, dim3(500), dim3(256), 0, stream,
                           Wf, bf, olen, ws, out, t);
    }
}